// Round 1
// baseline (616.194 us; speedup 1.0000x reference)
//
#include <hip/hip_runtime.h>

// ---------------------------------------------------------------------------
// SumAggregation: fused  y = BN(ReLU) chain over two 1x1-conv groups, masked
// scatter + prob weighting, summed over groups, output (B, COUT, M) fp32.
//
// Sizes (fixed by the reference):
//   B=4, M=32768, A = B*M/2 = 65536, CIN in {64,128}, HID=128, COUT=256.
// Mask is static: first M/2 slots of each row -> a = b*16384 + m.
//
// Pipeline (recompute, ws needs only 12KB):
//   P1: Z = Wa @ feats (bf16 MFMA), accumulate per-channel sum/sumsq (atomics)
//   finZ: scale/shift for BN1
//   P2: recompute Z, h = relu(bn(Z)) -> LDS, Y = Wb @ h, Y sum/sumsq
//   finY: scale/shift for BN2
//   P3: recompute Z,h,Y; out = relu(bn(Y)) * prob   (g0 writes, g1 adds)
//   zero_tail: out[:, :, M/2:] = 0
// ---------------------------------------------------------------------------

#define AT    65536
#define MFULL 32768
#define MHALF 16384

typedef __bf16 bf16_t;
typedef bf16_t bf16x8 __attribute__((ext_vector_type(8)));
typedef bf16_t bf16x4 __attribute__((ext_vector_type(4)));
typedef float  f32x4  __attribute__((ext_vector_type(4)));

__device__ __forceinline__ float redcol16(float v) {
  // sum across the 16 lanes sharing the same (lane>>4) group
  v += __shfl_xor(v, 1, 64);
  v += __shfl_xor(v, 2, 64);
  v += __shfl_xor(v, 4, 64);
  v += __shfl_xor(v, 8, 64);
  return v;
}

__device__ __forceinline__ bf16x8 cvt8(float4 a, float4 b) {
  bf16x8 r;
  r[0] = (bf16_t)a.x; r[1] = (bf16_t)a.y; r[2] = (bf16_t)a.z; r[3] = (bf16_t)a.w;
  r[4] = (bf16_t)b.x; r[5] = (bf16_t)b.y; r[6] = (bf16_t)b.z; r[7] = (bf16_t)b.w;
  return r;
}

// PHASE: 1 = Z-stats, 2 = Y-stats, 3 = write out, 4 = add to out
template <int CIN, int PHASE>
__global__ __launch_bounds__(256) void fused_mlp(
    const float* __restrict__ feats, const float* __restrict__ Wa,
    const float* __restrict__ Wb, const float* __restrict__ prob,
    float* __restrict__ zsum, float* __restrict__ zssq,
    const float* __restrict__ scaleZ, const float* __restrict__ shiftZ,
    float* __restrict__ ysum, float* __restrict__ yssq,
    const float* __restrict__ scaleY, const float* __restrict__ shiftY,
    float* __restrict__ out)
{
  constexpr int KS1 = CIN / 32;          // K-steps of GEMM1
  const int tid  = threadIdx.x;
  const int wid  = tid >> 6;             // wave id 0..3
  const int lane = tid & 63;
  const int lr   = lane & 15;            // MFMA row (A) / col (B,D)
  const int lk   = lane >> 4;            // MFMA k-group
  const int a0   = (int)blockIdx.x * 64; // 64-column tile

  // h tile: 16 cols x 128 k bf16, [col][k] with chunk-XOR swizzle (bank fix)
  __shared__ __align__(16) char hbuf[16 * 256];

  // ---- weight A-fragments (held in registers for the whole kernel) ----
  bf16x8 WaF[2][KS1];
#pragma unroll
  for (int mi = 0; mi < 2; ++mi) {
    const int row = (2 * wid + mi) * 16 + lr;
    const float* base = Wa + (size_t)row * CIN + lk * 8;
#pragma unroll
    for (int ks = 0; ks < KS1; ++ks) {
      const float4* p4 = reinterpret_cast<const float4*>(base + ks * 32);
      WaF[mi][ks] = cvt8(p4[0], p4[1]);
    }
  }

  bf16x8 WbF[4][4];
  if constexpr (PHASE >= 2) {
#pragma unroll
    for (int mi = 0; mi < 4; ++mi) {
      const int row = (4 * wid + mi) * 16 + lr;
      const float* base = Wb + (size_t)row * 128 + lk * 8;
#pragma unroll
      for (int ks = 0; ks < 4; ++ks) {
        const float4* p4 = reinterpret_cast<const float4*>(base + ks * 32);
        WbF[mi][ks] = cvt8(p4[0], p4[1]);
      }
    }
  }

  float sZ[2][4], bZ[2][4];
  if constexpr (PHASE >= 2) {
#pragma unroll
    for (int mi = 0; mi < 2; ++mi)
#pragma unroll
      for (int i = 0; i < 4; ++i) {
        const int ch = (2 * wid + mi) * 16 + lk * 4 + i;
        sZ[mi][i] = scaleZ[ch];
        bZ[mi][i] = shiftZ[ch];
      }
  }
  float sY[4][4], bY[4][4];
  if constexpr (PHASE >= 3) {
#pragma unroll
    for (int mi = 0; mi < 4; ++mi)
#pragma unroll
      for (int i = 0; i < 4; ++i) {
        const int ch = (4 * wid + mi) * 16 + lk * 4 + i;
        sY[mi][i] = scaleY[ch];
        bY[mi][i] = shiftY[ch];
      }
  }

  float zs[2][4] = {}, zq[2][4] = {};
  float ys[4][4] = {}, yq[4][4] = {};

  for (int nt = 0; nt < 4; ++nt) {
    const int colg = a0 + nt * 16 + lr;   // global active-column index a

    // ---------------- GEMM1: Z = Wa @ feats ----------------
    f32x4 zf[2];
    zf[0] = f32x4{0.f, 0.f, 0.f, 0.f};
    zf[1] = f32x4{0.f, 0.f, 0.f, 0.f};
#pragma unroll
    for (int ks = 0; ks < KS1; ++ks) {
      bf16x8 bfr;
      const float* fb = feats + (size_t)(ks * 32 + lk * 8) * AT + colg;
#pragma unroll
      for (int i = 0; i < 8; ++i) bfr[i] = (bf16_t)fb[(size_t)i * AT];
      zf[0] = __builtin_amdgcn_mfma_f32_16x16x32_bf16(WaF[0][ks], bfr, zf[0], 0, 0, 0);
      zf[1] = __builtin_amdgcn_mfma_f32_16x16x32_bf16(WaF[1][ks], bfr, zf[1], 0, 0, 0);
    }

    if constexpr (PHASE == 1) {
#pragma unroll
      for (int mi = 0; mi < 2; ++mi)
#pragma unroll
        for (int i = 0; i < 4; ++i) {
          const float z = zf[mi][i];
          zs[mi][i] += z;
          zq[mi][i] += z * z;
        }
    } else {
      // ---- h = relu(bn(Z)) -> LDS (bf16, swizzled [col][k]) ----
#pragma unroll
      for (int mi = 0; mi < 2; ++mi) {
        bf16x4 hv;
#pragma unroll
        for (int i = 0; i < 4; ++i) {
          float h = fmaxf(zf[mi][i] * sZ[mi][i] + bZ[mi][i], 0.f);
          hv[i] = (bf16_t)h;
        }
        const int chunk = (2 * wid + mi) * 2 + (lk >> 1); // 8-elem chunk of k
        const int addr = lr * 256 + ((chunk ^ (lr & 7)) << 4) + ((lk & 1) << 3);
        *reinterpret_cast<bf16x4*>(hbuf + addr) = hv;
      }
      __syncthreads();

      // ---------------- GEMM2: Y = Wb @ h ----------------
      f32x4 ya[4];
#pragma unroll
      for (int mi = 0; mi < 4; ++mi) ya[mi] = f32x4{0.f, 0.f, 0.f, 0.f};
#pragma unroll
      for (int ks2 = 0; ks2 < 4; ++ks2) {
        const int chunk = ks2 * 4 + lk;
        const bf16x8 hf = *reinterpret_cast<const bf16x8*>(
            hbuf + lr * 256 + ((chunk ^ (lr & 7)) << 4));
#pragma unroll
        for (int mi = 0; mi < 4; ++mi)
          ya[mi] = __builtin_amdgcn_mfma_f32_16x16x32_bf16(WbF[mi][ks2], hf, ya[mi], 0, 0, 0);
      }

      if constexpr (PHASE == 2) {
#pragma unroll
        for (int mi = 0; mi < 4; ++mi)
#pragma unroll
          for (int i = 0; i < 4; ++i) {
            const float y = ya[mi][i];
            ys[mi][i] += y;
            yq[mi][i] += y * y;
          }
      } else {
        const int b = colg >> 14;             // a / 16384
        const int m = colg & (MHALF - 1);     // a % 16384
        const float p = prob[((size_t)b << 15) + m];
#pragma unroll
        for (int mi = 0; mi < 4; ++mi)
#pragma unroll
          for (int i = 0; i < 4; ++i) {
            const int ch = (4 * wid + mi) * 16 + lk * 4 + i;
            const float v = fmaxf(ya[mi][i] * sY[mi][i] + bY[mi][i], 0.f) * p;
            float* o = out + (((size_t)(b * 256 + ch)) << 15) + m;
            if constexpr (PHASE == 3) *o = v;
            else                      *o += v;
          }
      }
      __syncthreads();   // protect hbuf before next nt overwrites it
    }
  }

  // ---- flush per-channel statistics ----
  if constexpr (PHASE == 1) {
#pragma unroll
    for (int mi = 0; mi < 2; ++mi)
#pragma unroll
      for (int i = 0; i < 4; ++i) {
        const float s = redcol16(zs[mi][i]);
        const float q = redcol16(zq[mi][i]);
        if (lr == 0) {
          const int ch = (2 * wid + mi) * 16 + lk * 4 + i;
          atomicAdd(&zsum[ch], s);
          atomicAdd(&zssq[ch], q);
        }
      }
  }
  if constexpr (PHASE == 2) {
#pragma unroll
    for (int mi = 0; mi < 4; ++mi)
#pragma unroll
      for (int i = 0; i < 4; ++i) {
        const float s = redcol16(ys[mi][i]);
        const float q = redcol16(yq[mi][i]);
        if (lr == 0) {
          const int ch = (4 * wid + mi) * 16 + lk * 4 + i;
          atomicAdd(&ysum[ch], s);
          atomicAdd(&yssq[ch], q);
        }
      }
  }
}

__global__ void finalize_stats(const float* __restrict__ sum,
                               const float* __restrict__ ssq,
                               const float* __restrict__ gamma0,
                               const float* __restrict__ beta0,
                               const float* __restrict__ gamma1,
                               const float* __restrict__ beta1,
                               float* __restrict__ scale,
                               float* __restrict__ shift, int nch)
{
  const int t = threadIdx.x;             // 2*nch threads
  const int g = t / nch;
  const int c = t - g * nch;
  const float inv = 1.f / 65536.f;       // 1/A
  const float mu  = sum[t] * inv;
  const float var = ssq[t] * inv - mu * mu;  // biased, like torch/jnp.var
  const float ga  = (g ? gamma1 : gamma0)[c];
  const float be  = (g ? beta1 : beta0)[c];
  const float sc  = ga * rsqrtf(var + 1e-5f);
  scale[t] = sc;
  shift[t] = be - mu * sc;
}

__global__ void zero_stats(float* __restrict__ ws) {
  const int t = threadIdx.x + blockIdx.x * blockDim.x;
  if (t < 1536) ws[t] = 0.f;
}

__global__ void zero_tail(float* __restrict__ out) {
  // out[(b*256+c)*32768 + 16384 .. 32767] = 0 ; as float4
  const unsigned total = 1024u * 4096u;  // (B*COUT) rows x 4096 float4
  for (unsigned i = threadIdx.x + blockIdx.x * blockDim.x; i < total;
       i += gridDim.x * blockDim.x) {
    const unsigned bc = i >> 12, r = i & 4095u;
    reinterpret_cast<float4*>(out)[(size_t)bc * 8192 + 4096 + r] =
        make_float4(0.f, 0.f, 0.f, 0.f);
  }
}

extern "C" void kernel_launch(void* const* d_in, const int* in_sizes, int n_in,
                              void* d_out, int out_size, void* d_ws, size_t ws_size,
                              hipStream_t stream)
{
  (void)in_sizes; (void)n_in; (void)out_size; (void)ws_size;
  const float* feats0 = (const float*)d_in[0];
  const float* feats1 = (const float*)d_in[1];
  const float* prob0  = (const float*)d_in[2];
  const float* prob1  = (const float*)d_in[3];
  const float* Wa0 = (const float*)d_in[6];
  const float* ga0 = (const float*)d_in[7];
  const float* ba0 = (const float*)d_in[8];
  const float* Wb0 = (const float*)d_in[9];
  const float* gb0 = (const float*)d_in[10];
  const float* bb0 = (const float*)d_in[11];
  const float* Wa1 = (const float*)d_in[12];
  const float* ga1 = (const float*)d_in[13];
  const float* ba1 = (const float*)d_in[14];
  const float* Wb1 = (const float*)d_in[15];
  const float* gb1 = (const float*)d_in[16];
  const float* bb1 = (const float*)d_in[17];

  float* out = (float*)d_out;
  float* ws  = (float*)d_ws;

  float* zsum   = ws;          // [2][128]
  float* zssq   = ws + 256;    // [2][128]
  float* ysum   = ws + 512;    // [2][256]
  float* yssq   = ws + 1024;   // [2][256]
  float* scaleZ = ws + 1536;   // [2][128]
  float* shiftZ = ws + 1792;   // [2][128]
  float* scaleY = ws + 2048;   // [2][256]
  float* shiftY = ws + 2560;   // [2][256]  (end = 3072 floats = 12KB)

  zero_stats<<<6, 256, 0, stream>>>(ws);
  zero_tail<<<2048, 256, 0, stream>>>(out);

  // ---- P1: Z statistics ----
  fused_mlp<64, 1><<<1024, 256, 0, stream>>>(feats0, Wa0, Wb0, prob0,
      zsum, zssq, scaleZ, shiftZ, ysum, yssq, scaleY, shiftY, out);
  fused_mlp<128, 1><<<1024, 256, 0, stream>>>(feats1, Wa1, Wb1, prob1,
      zsum + 128, zssq + 128, scaleZ + 128, shiftZ + 128,
      ysum + 256, yssq + 256, scaleY + 256, shiftY + 256, out);
  finalize_stats<<<1, 256, 0, stream>>>(zsum, zssq, ga0, ba0, ga1, ba1,
                                        scaleZ, shiftZ, 128);

  // ---- P2: Y statistics ----
  fused_mlp<64, 2><<<1024, 256, 0, stream>>>(feats0, Wa0, Wb0, prob0,
      zsum, zssq, scaleZ, shiftZ, ysum, yssq, scaleY, shiftY, out);
  fused_mlp<128, 2><<<1024, 256, 0, stream>>>(feats1, Wa1, Wb1, prob1,
      zsum + 128, zssq + 128, scaleZ + 128, shiftZ + 128,
      ysum + 256, yssq + 256, scaleY + 256, shiftY + 256, out);
  finalize_stats<<<1, 512, 0, stream>>>(ysum, yssq, gb0, bb0, gb1, bb1,
                                        scaleY, shiftY, 256);

  // ---- P3: final output (g0 writes, g1 accumulates) ----
  fused_mlp<64, 3><<<1024, 256, 0, stream>>>(feats0, Wa0, Wb0, prob0,
      zsum, zssq, scaleZ, shiftZ, ysum, yssq, scaleY, shiftY, out);
  fused_mlp<128, 4><<<1024, 256, 0, stream>>>(feats1, Wa1, Wb1, prob1,
      zsum + 128, zssq + 128, scaleZ + 128, shiftZ + 128,
      ysum + 256, yssq + 256, scaleY + 256, shiftY + 256, out);
}

// Round 2
// 414.225 us; speedup vs baseline: 1.4876x; 1.4876x over previous
//
#include <hip/hip_runtime.h>

// ---------------------------------------------------------------------------
// SumAggregation fused pipeline, v2.
//   out(B,COUT,M) = sum_g  scatter(relu(bn(Wb_g @ relu(bn(Wa_g @ feats_g))))) * prob_g
// Static mask: active col a = b*16384 + m, A = 65536.
//
// 3 fused dispatches (both groups in one kernel):
//   P1: Z-stats  P2: Y-stats  P3: write out.   Recompute pipeline, ws = 12KB.
//
// Column-interleaved tiling: block owns 64 cols, col(nt,lr) = a0 + lr*4 + nt.
//   -> feats loads are float4 (one load feeds all 4 nt MFMA tiles)
//   -> out stores are float4 (nt packs 4 consecutive m)
// One barrier per block (GEMM1 fully before GEMM2). h passes via 32KB LDS
// (16KB per group), [nt][slot][c] with chunk-XOR swizzle for b128 reads.
// ---------------------------------------------------------------------------

#define AT    65536
#define MHALF 16384

typedef __bf16 bf16_t;
typedef bf16_t bf16x8 __attribute__((ext_vector_type(8)));
typedef bf16_t bf16x4 __attribute__((ext_vector_type(4)));
typedef float  f32x4  __attribute__((ext_vector_type(4)));

__device__ __forceinline__ float redcol16(float v) {
  v += __shfl_xor(v, 1, 64);
  v += __shfl_xor(v, 2, 64);
  v += __shfl_xor(v, 4, 64);
  v += __shfl_xor(v, 8, 64);
  return v;
}

// ---- GEMM1 for one group: Z = Wa(128 x CIN) @ feats(CIN x A), 64-col tile.
// PHASE 1: accumulate Z stats.  PHASE>=2: h = relu(bn(Z)) -> hbuf (16KB).
template <int CIN, int PHASE>
__device__ __forceinline__ void gemm1_group(
    const float* __restrict__ feats, const float* __restrict__ Wa,
    float* __restrict__ zsum, float* __restrict__ zssq,
    const float* __restrict__ scaleZ, const float* __restrict__ shiftZ,
    char* __restrict__ hbuf)
{
  constexpr int KS1 = CIN / 32;
  const int tid = threadIdx.x, wid = tid >> 6, lane = tid & 63;
  const int lr = lane & 15, lk = lane >> 4;
  const int colbase = (int)blockIdx.x * 64 + lr * 4;

  // A-fragments: rows (2*wid+mi)*16 + lr, k = ks*32 + lk*8 + j
  bf16x8 WaF[2][KS1];
#pragma unroll
  for (int mi = 0; mi < 2; ++mi) {
    const float* base = Wa + (size_t)((2 * wid + mi) * 16 + lr) * CIN + lk * 8;
#pragma unroll
    for (int ks = 0; ks < KS1; ++ks) {
      const f32x4 a = *reinterpret_cast<const f32x4*>(base + ks * 32);
      const f32x4 b = *reinterpret_cast<const f32x4*>(base + ks * 32 + 4);
#pragma unroll
      for (int j = 0; j < 4; ++j) {
        WaF[mi][ks][j]     = (bf16_t)a[j];
        WaF[mi][ks][4 + j] = (bf16_t)b[j];
      }
    }
  }

  f32x4 zacc[4][2];
#pragma unroll
  for (int nt = 0; nt < 4; ++nt) {
    zacc[nt][0] = f32x4{0.f, 0.f, 0.f, 0.f};
    zacc[nt][1] = f32x4{0.f, 0.f, 0.f, 0.f};
  }

#pragma unroll
  for (int ks = 0; ks < KS1; ++ks) {
    const float* fb = feats + (size_t)(ks * 32 + lk * 8) * AT + colbase;
    f32x4 v[8];
#pragma unroll
    for (int j = 0; j < 8; ++j)
      v[j] = *reinterpret_cast<const f32x4*>(fb + (size_t)j * AT);
#pragma unroll
    for (int nt = 0; nt < 4; ++nt) {
      bf16x8 bfr;
#pragma unroll
      for (int j = 0; j < 8; ++j) bfr[j] = (bf16_t)v[j][nt];
      zacc[nt][0] = __builtin_amdgcn_mfma_f32_16x16x32_bf16(WaF[0][ks], bfr, zacc[nt][0], 0, 0, 0);
      zacc[nt][1] = __builtin_amdgcn_mfma_f32_16x16x32_bf16(WaF[1][ks], bfr, zacc[nt][1], 0, 0, 0);
    }
  }

  if constexpr (PHASE == 1) {
#pragma unroll
    for (int mi = 0; mi < 2; ++mi)
#pragma unroll
      for (int i = 0; i < 4; ++i) {
        float s = 0.f, q = 0.f;
#pragma unroll
        for (int nt = 0; nt < 4; ++nt) {
          const float z = zacc[nt][mi][i];
          s += z; q += z * z;
        }
        s = redcol16(s); q = redcol16(q);
        if (lr == 0) {
          const int ch = (2 * wid + mi) * 16 + lk * 4 + i;
          atomicAdd(&zsum[ch], s);
          atomicAdd(&zssq[ch], q);
        }
      }
  } else {
    float sZ[2][4], bZ[2][4];
#pragma unroll
    for (int mi = 0; mi < 2; ++mi)
#pragma unroll
      for (int i = 0; i < 4; ++i) {
        const int ch = (2 * wid + mi) * 16 + lk * 4 + i;
        sZ[mi][i] = scaleZ[ch];
        bZ[mi][i] = shiftZ[ch];
      }
#pragma unroll
    for (int nt = 0; nt < 4; ++nt)
#pragma unroll
      for (int mi = 0; mi < 2; ++mi) {
        bf16x4 hv;
#pragma unroll
        for (int i = 0; i < 4; ++i)
          hv[i] = (bf16_t)fmaxf(zacc[nt][mi][i] * sZ[mi][i] + bZ[mi][i], 0.f);
        // channel base c = (2*wid+mi)*16 + lk*4; chunk = c>>3, half-sel = lk&1
        const int chunk = (2 * wid + mi) * 2 + (lk >> 1);
        const int addr = nt * 4096 + lr * 256 + ((chunk ^ (lr & 7)) << 4) + ((lk & 1) << 3);
        *reinterpret_cast<bf16x4*>(hbuf + addr) = hv;
      }
  }
}

// ---- GEMM2 half-pass for one group: rows [half*128, half*128+128) of COUT.
// PHASE 2: accumulate Y stats.  PHASE 3: oval += relu(bn(Y)) * prob.
template <int PHASE>
__device__ __forceinline__ void gemm2_group(
    const char* __restrict__ hbuf, const float* __restrict__ Wb,
    const float* __restrict__ prob,
    float* __restrict__ ysum, float* __restrict__ yssq,
    const float* __restrict__ scaleY, const float* __restrict__ shiftY,
    int half, float (&oval)[4][2][4])
{
  const int tid = threadIdx.x, wid = tid >> 6, lane = tid & 63;
  const int lr = lane & 15, lk = lane >> 4;

  bf16x8 WbF[2][4];
#pragma unroll
  for (int mi = 0; mi < 2; ++mi) {
    const float* base = Wb + (size_t)(half * 128 + (2 * wid + mi) * 16 + lr) * 128 + lk * 8;
#pragma unroll
    for (int ks = 0; ks < 4; ++ks) {
      const f32x4 a = *reinterpret_cast<const f32x4*>(base + ks * 32);
      const f32x4 b = *reinterpret_cast<const f32x4*>(base + ks * 32 + 4);
#pragma unroll
      for (int j = 0; j < 4; ++j) {
        WbF[mi][ks][j]     = (bf16_t)a[j];
        WbF[mi][ks][4 + j] = (bf16_t)b[j];
      }
    }
  }

  float sY[2][4], bY[2][4];
  f32x4 p4;
  if constexpr (PHASE == 3) {
#pragma unroll
    for (int mi = 0; mi < 2; ++mi)
#pragma unroll
      for (int i = 0; i < 4; ++i) {
        const int ch = half * 128 + (2 * wid + mi) * 16 + lk * 4 + i;
        sY[mi][i] = scaleY[ch];
        bY[mi][i] = shiftY[ch];
      }
    const int col0 = (int)blockIdx.x * 64 + lr * 4;
    p4 = *reinterpret_cast<const f32x4*>(
        prob + (((size_t)(col0 >> 14)) << 15) + (col0 & (MHALF - 1)));
  }

  float ys[2][4] = {}, yq[2][4] = {};

#pragma unroll
  for (int nt = 0; nt < 4; ++nt) {
    f32x4 yacc[2];
    yacc[0] = f32x4{0.f, 0.f, 0.f, 0.f};
    yacc[1] = f32x4{0.f, 0.f, 0.f, 0.f};
#pragma unroll
    for (int ks = 0; ks < 4; ++ks) {
      const int chunk = ks * 4 + lk;
      const bf16x8 hf = *reinterpret_cast<const bf16x8*>(
          hbuf + nt * 4096 + lr * 256 + ((chunk ^ (lr & 7)) << 4));
      yacc[0] = __builtin_amdgcn_mfma_f32_16x16x32_bf16(WbF[0][ks], hf, yacc[0], 0, 0, 0);
      yacc[1] = __builtin_amdgcn_mfma_f32_16x16x32_bf16(WbF[1][ks], hf, yacc[1], 0, 0, 0);
    }
    if constexpr (PHASE == 2) {
#pragma unroll
      for (int mi = 0; mi < 2; ++mi)
#pragma unroll
        for (int i = 0; i < 4; ++i) {
          const float y = yacc[mi][i];
          ys[mi][i] += y; yq[mi][i] += y * y;
        }
    } else {
#pragma unroll
      for (int mi = 0; mi < 2; ++mi)
#pragma unroll
        for (int i = 0; i < 4; ++i)
          oval[nt][mi][i] += fmaxf(yacc[mi][i] * sY[mi][i] + bY[mi][i], 0.f) * p4[nt];
    }
  }

  if constexpr (PHASE == 2) {
#pragma unroll
    for (int mi = 0; mi < 2; ++mi)
#pragma unroll
      for (int i = 0; i < 4; ++i) {
        const float s = redcol16(ys[mi][i]);
        const float q = redcol16(yq[mi][i]);
        if (lr == 0) {
          const int ch = half * 128 + (2 * wid + mi) * 16 + lk * 4 + i;
          atomicAdd(&ysum[ch], s);
          atomicAdd(&yssq[ch], q);
        }
      }
  }
}

template <int PHASE>
__global__ __launch_bounds__(256) void fused_all(
    const float* __restrict__ feats0, const float* __restrict__ feats1,
    const float* __restrict__ Wa0, const float* __restrict__ Wb0,
    const float* __restrict__ Wa1, const float* __restrict__ Wb1,
    const float* __restrict__ prob0, const float* __restrict__ prob1,
    float* __restrict__ zsum, float* __restrict__ zssq,
    const float* __restrict__ scaleZ, const float* __restrict__ shiftZ,
    float* __restrict__ ysum, float* __restrict__ yssq,
    const float* __restrict__ scaleY, const float* __restrict__ shiftY,
    float* __restrict__ out)
{
  __shared__ __align__(16) char hbuf[2][16384];

  gemm1_group<64, PHASE>(feats0, Wa0, zsum, zssq, scaleZ, shiftZ, hbuf[0]);
  gemm1_group<128, PHASE>(feats1, Wa1, zsum + 128, zssq + 128,
                          scaleZ + 128, shiftZ + 128, hbuf[1]);

  if constexpr (PHASE == 1) return;

  __syncthreads();   // the only barrier: h tiles ready

  const int tid = threadIdx.x, wid = tid >> 6, lane = tid & 63;
  const int lr = lane & 15, lk = lane >> 6 ? 0 : (lane >> 4);  // lk recompute
  const int lkk = (lane >> 4);

#pragma unroll
  for (int half = 0; half < 2; ++half) {
    float oval[4][2][4];
    if constexpr (PHASE == 3) {
#pragma unroll
      for (int nt = 0; nt < 4; ++nt)
#pragma unroll
        for (int mi = 0; mi < 2; ++mi)
#pragma unroll
          for (int i = 0; i < 4; ++i) oval[nt][mi][i] = 0.f;
    }
    gemm2_group<PHASE>(hbuf[0], Wb0, prob0, ysum, yssq,
                       scaleY, shiftY, half, oval);
    gemm2_group<PHASE>(hbuf[1], Wb1, prob1, ysum + 256, yssq + 256,
                       scaleY + 256, shiftY + 256, half, oval);
    if constexpr (PHASE == 3) {
      const int col0 = (int)blockIdx.x * 64 + lr * 4;
      const int b = col0 >> 14, m0 = col0 & (MHALF - 1);
#pragma unroll
      for (int mi = 0; mi < 2; ++mi)
#pragma unroll
        for (int i = 0; i < 4; ++i) {
          const int ch = half * 128 + wid * 32 + mi * 16 + lkk * 4 + i;
          f32x4 w;
#pragma unroll
          for (int nt = 0; nt < 4; ++nt) w[nt] = oval[nt][mi][i];
          *reinterpret_cast<f32x4*>(
              out + (((size_t)(b * 256 + ch)) << 15) + m0) = w;
        }
    }
  }
  (void)lk;
}

__global__ void finalize_stats(const float* __restrict__ sum,
                               const float* __restrict__ ssq,
                               const float* __restrict__ gamma0,
                               const float* __restrict__ beta0,
                               const float* __restrict__ gamma1,
                               const float* __restrict__ beta1,
                               float* __restrict__ scale,
                               float* __restrict__ shift, int nch)
{
  const int t = threadIdx.x;             // 2*nch threads
  const int g = t / nch;
  const int c = t - g * nch;
  const float inv = 1.f / 65536.f;       // 1/A
  const float mu  = sum[t] * inv;
  const float var = ssq[t] * inv - mu * mu;  // biased variance
  const float ga  = (g ? gamma1 : gamma0)[c];
  const float be  = (g ? beta1 : beta0)[c];
  const float sc  = ga * rsqrtf(var + 1e-5f);
  scale[t] = sc;
  shift[t] = be - mu * sc;
}

__global__ void zero_stats(float* __restrict__ ws) {
  const int t = threadIdx.x + blockIdx.x * blockDim.x;
  if (t < 1536) ws[t] = 0.f;
}

__global__ void zero_tail(float* __restrict__ out) {
  const unsigned total = 1024u * 4096u;  // (B*COUT) rows x 4096 float4
  for (unsigned i = threadIdx.x + blockIdx.x * blockDim.x; i < total;
       i += gridDim.x * blockDim.x) {
    const unsigned bc = i >> 12, r = i & 4095u;
    reinterpret_cast<float4*>(out)[(size_t)bc * 8192 + 4096 + r] =
        make_float4(0.f, 0.f, 0.f, 0.f);
  }
}

extern "C" void kernel_launch(void* const* d_in, const int* in_sizes, int n_in,
                              void* d_out, int out_size, void* d_ws, size_t ws_size,
                              hipStream_t stream)
{
  (void)in_sizes; (void)n_in; (void)out_size; (void)ws_size;
  const float* feats0 = (const float*)d_in[0];
  const float* feats1 = (const float*)d_in[1];
  const float* prob0  = (const float*)d_in[2];
  const float* prob1  = (const float*)d_in[3];
  const float* Wa0 = (const float*)d_in[6];
  const float* ga0 = (const float*)d_in[7];
  const float* ba0 = (const float*)d_in[8];
  const float* Wb0 = (const float*)d_in[9];
  const float* gb0 = (const float*)d_in[10];
  const float* bb0 = (const float*)d_in[11];
  const float* Wa1 = (const float*)d_in[12];
  const float* ga1 = (const float*)d_in[13];
  const float* ba1 = (const float*)d_in[14];
  const float* Wb1 = (const float*)d_in[15];
  const float* gb1 = (const float*)d_in[16];
  const float* bb1 = (const float*)d_in[17];

  float* out = (float*)d_out;
  float* ws  = (float*)d_ws;

  float* zsum   = ws;          // [2][128]
  float* zssq   = ws + 256;    // [2][128]
  float* ysum   = ws + 512;    // [2][256]
  float* yssq   = ws + 1024;   // [2][256]
  float* scaleZ = ws + 1536;   // [2][128]
  float* shiftZ = ws + 1792;   // [2][128]
  float* scaleY = ws + 2048;   // [2][256]
  float* shiftY = ws + 2560;   // [2][256]

  zero_stats<<<6, 256, 0, stream>>>(ws);
  zero_tail<<<2048, 256, 0, stream>>>(out);

  fused_all<1><<<1024, 256, 0, stream>>>(feats0, feats1, Wa0, Wb0, Wa1, Wb1,
      prob0, prob1, zsum, zssq, scaleZ, shiftZ, ysum, yssq, scaleY, shiftY, out);
  finalize_stats<<<1, 256, 0, stream>>>(zsum, zssq, ga0, ba0, ga1, ba1,
                                        scaleZ, shiftZ, 128);
  fused_all<2><<<1024, 256, 0, stream>>>(feats0, feats1, Wa0, Wb0, Wa1, Wb1,
      prob0, prob1, zsum, zssq, scaleZ, shiftZ, ysum, yssq, scaleY, shiftY, out);
  finalize_stats<<<1, 512, 0, stream>>>(ysum, yssq, gb0, bb0, gb1, bb1,
                                        scaleY, shiftY, 256);
  fused_all<3><<<1024, 256, 0, stream>>>(feats0, feats1, Wa0, Wb0, Wa1, Wb1,
      prob0, prob1, zsum, zssq, scaleZ, shiftZ, ysum, yssq, scaleY, shiftY, out);
}